// Round 9
// baseline (1220.579 us; speedup 1.0000x reference)
//
#include <hip/hip_runtime.h>

#define TT 256
#define BB 32
#define HH 512
#define EE 512
#define GG 2048
#define MM 8192
#define NWG 32   // workgroups per direction in lstm_rec

typedef __attribute__((ext_vector_type(8))) short bf16x8;
typedef __attribute__((ext_vector_type(4))) float f32x4;
typedef __attribute__((ext_vector_type(4))) unsigned short us4;
typedef unsigned long long ull;

__device__ inline float b2f(unsigned short u) {
    union { unsigned int i; float f; } v; v.i = ((unsigned int)u) << 16; return v.f;
}
__device__ inline unsigned short f2b(float f) {
    union { float f; unsigned int i; } v; v.f = f;
    unsigned int x = v.i;
    return (unsigned short)((x + 0x7FFFu + ((x >> 16) & 1u)) >> 16);
}
__device__ inline float sigm(float x) { return 1.f / (1.f + __expf(-x)); }
__device__ inline float tanh_f(float x) {
    float ax = fminf(fabsf(x), 12.f);
    float e = __expf(2.f * ax);
    float r = (e - 1.f) / (e + 1.f);
    return x < 0.f ? -r : r;
}

// ---------------- prep + embed fused ----------------
__global__ void prep_embed_k(const int* __restrict__ ids, const float* __restrict__ emb,
                             const float* __restrict__ wihf, const float* __restrict__ whhf,
                             const float* __restrict__ wihb, const float* __restrict__ whhb,
                             const float* __restrict__ bihf, const float* __restrict__ bhhf,
                             const float* __restrict__ bihb, const float* __restrict__ bhhb,
                             unsigned short* __restrict__ xb, unsigned short* __restrict__ wih,
                             unsigned short* __restrict__ whh, float* __restrict__ bias)
{
    int v = blockIdx.x * 256 + threadIdx.x;   // 0..1048575
    {   // embedding: x[row][col4..col4+3]
        int row = v >> 7;
        int col4 = (v & 127) * 4;
        int id = ids[row];
        float4 e;
        if (id != 0) e = *(const float4*)(emb + (size_t)id * 512 + col4);
        else { e.x = 0.f; e.y = 0.f; e.z = 0.f; e.w = 0.f; }
        us4 o; o.x = f2b(e.x); o.y = f2b(e.y); o.z = f2b(e.z); o.w = f2b(e.w);
        *(us4*)(xb + (size_t)row * 512 + col4) = o;
    }
    if (v < 262144) {   // weight convert + bias sums
        float4 a; us4 o;
        a = ((const float4*)wihf)[v];
        o.x = f2b(a.x); o.y = f2b(a.y); o.z = f2b(a.z); o.w = f2b(a.w);
        *(us4*)(wih + (size_t)v * 4) = o;
        a = ((const float4*)whhf)[v];
        o.x = f2b(a.x); o.y = f2b(a.y); o.z = f2b(a.z); o.w = f2b(a.w);
        *(us4*)(whh + (size_t)v * 4) = o;
        a = ((const float4*)wihb)[v];
        o.x = f2b(a.x); o.y = f2b(a.y); o.z = f2b(a.z); o.w = f2b(a.w);
        *(us4*)(wih + 1048576 + (size_t)v * 4) = o;
        a = ((const float4*)whhb)[v];
        o.x = f2b(a.x); o.y = f2b(a.y); o.z = f2b(a.z); o.w = f2b(a.w);
        *(us4*)(whh + 1048576 + (size_t)v * 4) = o;
        if (v < 2048)      bias[v] = bihf[v] + bhhf[v];
        else if (v < 4096) bias[v] = bihb[v - 2048] + bhhb[v - 2048];
    }
}

// ---------------- persistent bidirectional LSTM with fused input GEMM ----------------
// grid 64: dir = bx>>5, wg = bx&31 owns hidden cols [wg*16, wg*16+16). 1 WG/CU.
// Round-8 structure with ONE change: the x-MFMA is moved AFTER the h-gather loads
// are issued, so its ~600cy execute under the gather's LLC round-trip instead of
// serially before the poll.
__global__ __launch_bounds__(256, 1) void lstm_rec(const unsigned short* __restrict__ whh,
                                                   const unsigned short* __restrict__ wih,
                                                   const unsigned short* __restrict__ xb,
                                                   const float* __restrict__ bias,
                                                   unsigned short* __restrict__ h_all,
                                                   unsigned int* __restrict__ cnt)
{
    __shared__ unsigned short hbuf[32][520];      // h_{t-1} staging
    __shared__ unsigned short xbuf[2][32][520];   // x_t staging, double-buffered
    __shared__ float gbuf[4][32][16];             // gate pre-activations

    const int bx = blockIdx.x;
    const int dir = bx >> 5;
    const int wg = bx & 31;
    const int js = wg * 16;
    const int tid = threadIdx.x;
    const int wave = tid >> 6, lane = tid & 63;
    const int quad = lane >> 4, r16 = lane & 15;
    const int colw = wave * 512 + js + r16;       // gate-row in whh/wih

    // B-fragments: this WG's w_hh and w_ih slices, in registers (64+64 VGPRs)
    bf16x8 wfr[16], xfr[16];
    {
        const unsigned short* wrow = whh + (size_t)dir * GG * HH + (size_t)colw * 512;
        const unsigned short* xrow = wih + (size_t)dir * GG * EE + (size_t)colw * 512;
#pragma unroll
        for (int kc = 0; kc < 16; ++kc) {
            wfr[kc] = *(const bf16x8*)(wrow + kc * 32 + quad * 8);
            xfr[kc] = *(const bf16x8*)(xrow + kc * 32 + quad * 8);
        }
    }
    const float bsw = bias[dir * GG + colw];

    // cell state in registers: thread owns (b = tid>>3, j = js + 2*(tid&7) + {0,1})
    const int cb = tid >> 3, cj = (tid & 7) * 2;
    float cr0 = 0.f, cr1 = 0.f;

    unsigned short* hd = h_all + (size_t)dir * TT * BB * HH;
    unsigned int* flg = cnt + dir * NWG;
    const ull* xbsrc = (const ull*)xb;            // 64 ull per 512-col row

    // prologue: stage x for the first step into xbuf[0]
    {
        const int te0 = dir ? (TT - 1) : 0;
#pragma unroll
        for (int i = 0; i < 16; ++i) {
            int v = tid + i * 256;
            int row = v >> 7, wi = v & 127;
            ull xv = xbsrc[(size_t)((row << 8) + te0) * 64 + wi];
            *(ull*)&xbuf[0][row][wi * 4] = xv;
        }
    }
    __syncthreads();
    int buf = 0;

    for (int t = 0; t < TT; ++t) {
        const int te = dir ? (TT - 1 - t) : t;

        // issue next step's x prefetch (held in regs; written to LDS at step end)
        ull xpre[16];
        if (t + 1 < TT) {
            const int tn = dir ? (te - 1) : (te + 1);
#pragma unroll
            for (int i = 0; i < 16; ++i) {
                int v = tid + i * 256;
                int row = v >> 7, wi = v & 127;
                xpre[i] = xbsrc[(size_t)((row << 8) + tn) * 64 + wi];
            }
        }

        f32x4 alo = {0.f, 0.f, 0.f, 0.f}, ahi = {0.f, 0.f, 0.f, 0.f};

        if (t == 0) {
            // x-MFMA only (h0 = 0)
#pragma unroll
            for (int kc = 0; kc < 16; ++kc) {
                const int ko = kc * 32 + quad * 8;
                bf16x8 aflo = *(const bf16x8*)&xbuf[buf][r16][ko];
                bf16x8 afhi = *(const bf16x8*)&xbuf[buf][16 + r16][ko];
                alo = __builtin_amdgcn_mfma_f32_16x16x32_bf16(aflo, xfr[kc], alo, 0, 0, 0);
                ahi = __builtin_amdgcn_mfma_f32_16x16x32_bf16(afhi, xfr[kc], ahi, 0, 0, 0);
            }
        } else {
            if (wave == 0) {
                const unsigned int tgt = (unsigned int)t;
                for (;;) {
                    unsigned int f = tgt;
                    if (lane < NWG)
                        f = __hip_atomic_load(&flg[lane], __ATOMIC_RELAXED, __HIP_MEMORY_SCOPE_AGENT);
                    if (__ballot(f >= tgt) == ~0ull) break;
                }
            }
            __syncthreads();   // B0: flag confirmed for all waves

            // issue h gather loads (LLC RT in flight during x-MFMA below)
            const int tp = dir ? (te + 1) : (te - 1);
            const ull* hsrc = (const ull*)(hd + (size_t)tp * BB * HH);
            ull hv[16];
#pragma unroll
            for (int i = 0; i < 16; ++i)
                hv[i] = __hip_atomic_load(&hsrc[tid + i * 256], __ATOMIC_RELAXED, __HIP_MEMORY_SCOPE_AGENT);

            // x-MFMA: reads xbuf only — overlaps the gather round-trip
#pragma unroll
            for (int kc = 0; kc < 16; ++kc) {
                const int ko = kc * 32 + quad * 8;
                bf16x8 aflo = *(const bf16x8*)&xbuf[buf][r16][ko];
                bf16x8 afhi = *(const bf16x8*)&xbuf[buf][16 + r16][ko];
                alo = __builtin_amdgcn_mfma_f32_16x16x32_bf16(aflo, xfr[kc], alo, 0, 0, 0);
                ahi = __builtin_amdgcn_mfma_f32_16x16x32_bf16(afhi, xfr[kc], ahi, 0, 0, 0);
            }

            // land gathered h into LDS (vmcnt wait here, mostly drained already)
#pragma unroll
            for (int i = 0; i < 16; ++i) {
                int v = tid + i * 256;
                *(ull*)&hbuf[v >> 7][(v & 127) * 4] = hv[i];
            }
            __syncthreads();   // B1: hbuf ready

#pragma unroll
            for (int kc = 0; kc < 16; ++kc) {
                const int ko = kc * 32 + quad * 8;
                bf16x8 aflo = *(const bf16x8*)&hbuf[r16][ko];
                bf16x8 afhi = *(const bf16x8*)&hbuf[16 + r16][ko];
                alo = __builtin_amdgcn_mfma_f32_16x16x32_bf16(aflo, wfr[kc], alo, 0, 0, 0);
                ahi = __builtin_amdgcn_mfma_f32_16x16x32_bf16(afhi, wfr[kc], ahi, 0, 0, 0);
            }
        }

#pragma unroll
        for (int r = 0; r < 4; ++r) {
            gbuf[wave][quad * 4 + r][r16]      = alo[r] + bsw;
            gbuf[wave][16 + quad * 4 + r][r16] = ahi[r] + bsw;
        }
        __syncthreads();   // B2: gbuf ready (and all hbuf/xbuf reads done)

        // nonlinearity: thread owns (cb, cj) and (cb, cj+1)
        {
            float2 iv = *(const float2*)&gbuf[0][cb][cj];
            float2 fv = *(const float2*)&gbuf[1][cb][cj];
            float2 gv = *(const float2*)&gbuf[2][cb][cj];
            float2 ov = *(const float2*)&gbuf[3][cb][cj];
            cr0 = sigm(fv.x) * cr0 + sigm(iv.x) * tanh_f(gv.x);
            cr1 = sigm(fv.y) * cr1 + sigm(iv.y) * tanh_f(gv.y);
            float h0 = sigm(ov.x) * tanh_f(cr0);
            float h1 = sigm(ov.y) * tanh_f(cr1);
            unsigned int packed = (unsigned int)f2b(h0) | ((unsigned int)f2b(h1) << 16);
            unsigned int* hp = (unsigned int*)(hd + (size_t)te * BB * HH + cb * 512 + js + cj);
            __hip_atomic_store(hp, packed, __ATOMIC_RELAXED, __HIP_MEMORY_SCOPE_AGENT);
        }

        // write prefetched x into the other buffer (overlaps h-store drain)
        if (t + 1 < TT) {
#pragma unroll
            for (int i = 0; i < 16; ++i) {
                int v = tid + i * 256;
                *(ull*)&xbuf[buf ^ 1][v >> 7][(v & 127) * 4] = xpre[i];
            }
            buf ^= 1;
        }
        __syncthreads();   // B3: vmcnt drained (h stores acked) + xbuf[new] ready
        if (tid == 0)
            __hip_atomic_store(&flg[wg], (unsigned int)(t + 1),
                               __ATOMIC_RELAXED, __HIP_MEMORY_SCOPE_AGENT);
    }
}

// ---------------- fused tail: logits -> CRF -> -mean accumulate ----------------
// 32 WGs (one per batch), 256 threads. Wave w computes logits for t in [w*64, w*64+64)
// into LDS (proven logits_k inner loop). Then wave 0 runs the CRF forward
// wave-synchronously (alpha in registers, shfl broadcast, NO barriers in the loop,
// logits from LDS). Each WG atomicAdds -llh[b]/32 into out[0] (pre-zeroed).
__global__ __launch_bounds__(256) void tail_k(const unsigned short* __restrict__ h_all,
                                              const float* __restrict__ clsw,
                                              const float* __restrict__ clsb,
                                              const int* __restrict__ label,
                                              const float* __restrict__ startp,
                                              const float* __restrict__ endp,
                                              const float* __restrict__ trans,
                                              float* __restrict__ out)
{
    __shared__ float lgt_s[TT][9];
    __shared__ float trs[81];
    __shared__ int tags[TT];

    const int b = blockIdx.x;
    const int tid = threadIdx.x;
    const int wave = tid >> 6, lane = tid & 63;

    for (int v = tid; v < 81; v += 256) trs[v] = trans[v];
    for (int v = tid; v < TT; v += 256) tags[v] = label[b * TT + v];

    // ---- logits phase (all 4 waves) ----
    unsigned int wreg[9][8];
#pragma unroll
    for (int c = 0; c < 9; ++c)
#pragma unroll
        for (int q = 0; q < 8; ++q) {
            float w0 = clsw[c * 1024 + (2 * q) * 64 + lane];
            float w1 = clsw[c * 1024 + (2 * q + 1) * 64 + lane];
            wreg[c][q] = (unsigned int)f2b(w0) | ((unsigned int)f2b(w1) << 16);
        }
    const unsigned short* hfb = h_all;
    const unsigned short* hbb = h_all + (size_t)TT * BB * HH;

    for (int i = 0; i < 64; ++i) {
        int t = wave * 64 + i;
        const unsigned short* hf = hfb + ((size_t)t * BB + b) * HH;
        const unsigned short* hb = hbb + ((size_t)t * BB + b) * HH;
        float acc[9];
#pragma unroll
        for (int c = 0; c < 9; ++c) acc[c] = 0.f;
#pragma unroll
        for (int u = 0; u < 16; ++u) {
            const unsigned short* src = (u < 8) ? (hf + u * 64) : (hb + (u - 8) * 64);
            float hv = b2f(src[lane]);
#pragma unroll
            for (int c = 0; c < 9; ++c) {
                unsigned short wv = (u & 1) ? (unsigned short)(wreg[c][u >> 1] >> 16)
                                            : (unsigned short)(wreg[c][u >> 1] & 0xFFFFu);
                acc[c] += hv * b2f(wv);
            }
        }
#pragma unroll
        for (int c = 0; c < 9; ++c) {
            float s = acc[c];
            for (int off = 32; off > 0; off >>= 1) s += __shfl_down(s, off);
            if (lane == 0) lgt_s[t][c] = s + clsb[c];
        }
    }
    __syncthreads();   // lgt_s / trs / tags ready

    // ---- CRF phase (wave 0 only; wave-synchronous, no barriers) ----
    if (wave == 0) {
        // numerator (64 lanes)
        float part = 0.f; int mcnt = 0;
        for (int t = lane; t < TT; t += 64) {
            int tg = tags[t];
            bool m = tg > -1;
            if (m) mcnt++;
            if (t == 0)      part += startp[tg] + lgt_s[0][tg];
            else if (m)      part += lgt_s[t][tg] + trs[tags[t - 1] * 9 + tg];
        }
        for (int off = 32; off > 0; off >>= 1) {
            part += __shfl_down(part, off);
            mcnt += __shfl_down(mcnt, off);
        }
        part = __shfl(part, 0);
        mcnt = __shfl(mcnt, 0);
        float num = part + endp[tags[mcnt - 1]];

        // forward: alpha in registers (lane c holds alpha_c for c<9)
        const int cme = (lane < 9) ? lane : 0;
        float trr[9];
#pragma unroll
        for (int c1 = 0; c1 < 9; ++c1) trr[c1] = trs[c1 * 9 + cme];
        float av = startp[cme] + lgt_s[0][cme];

        for (int t = 1; t < TT; ++t) {
            float sh[9];
#pragma unroll
            for (int c1 = 0; c1 < 9; ++c1) sh[c1] = __shfl(av, c1) + trr[c1];
            float mx = sh[0];
#pragma unroll
            for (int c1 = 1; c1 < 9; ++c1) mx = fmaxf(mx, sh[c1]);
            float s = 0.f;
#pragma unroll
            for (int c1 = 0; c1 < 9; ++c1) s += __expf(sh[c1] - mx);
            float nxt = mx + __logf(s) + lgt_s[t][cme];
            if (tags[t] > -1) av = nxt;   // lanes >=9 carry garbage, never read
        }

        // denominator: logsumexp over lanes 0..8 of av + endp
        float fin = av + endp[cme];
        float acs[9];
#pragma unroll
        for (int c = 0; c < 9; ++c) acs[c] = __shfl(fin, c);
        if (lane == 0) {
            float mx = acs[0];
#pragma unroll
            for (int c = 1; c < 9; ++c) mx = fmaxf(mx, acs[c]);
            float s = 0.f;
#pragma unroll
            for (int c = 0; c < 9; ++c) s += __expf(acs[c] - mx);
            float den = mx + __logf(s);
            atomicAdd(out, -(num - den) * (1.f / 32.f));
        }
    }
}

// ---------------- launch ----------------
extern "C" void kernel_launch(void* const* d_in, const int* in_sizes, int n_in,
                              void* d_out, int out_size, void* d_ws, size_t ws_size,
                              hipStream_t stream)
{
    const int*   ids   = (const int*)  d_in[0];
    const int*   label = (const int*)  d_in[1];
    const float* emb   = (const float*)d_in[2];
    const float* wihf  = (const float*)d_in[3];
    const float* whhf  = (const float*)d_in[4];
    const float* bihf  = (const float*)d_in[5];
    const float* bhhf  = (const float*)d_in[6];
    const float* wihb  = (const float*)d_in[7];
    const float* whhb  = (const float*)d_in[8];
    const float* bihb  = (const float*)d_in[9];
    const float* bhhb  = (const float*)d_in[10];
    const float* clsw  = (const float*)d_in[11];
    const float* clsb  = (const float*)d_in[12];
    const float* stp   = (const float*)d_in[13];
    const float* enp   = (const float*)d_in[14];
    const float* trp   = (const float*)d_in[15];

    char* ws = (char*)d_ws;
    unsigned short* xb   = (unsigned short*)(ws + 0);           //  8 MB  [8192][512] bf16
    unsigned short* wih  = (unsigned short*)(ws + 8388608);     //  4 MB  [2][2048][512]
    unsigned short* whh  = (unsigned short*)(ws + 12582912);    //  4 MB  [2][2048][512]
    float*          bias = (float*)(ws + 16777216);             // 16 KB  [2][2048]
    unsigned short* hall = (unsigned short*)(ws + 16793600);    // 16 MB  [2][256][32][512]
    unsigned int*   cnt  = (unsigned int*)(ws + 33570816);      // flags [2][32]

    hipMemsetAsync(cnt, 0, 256, stream);
    hipMemsetAsync(d_out, 0, sizeof(float), stream);
    prep_embed_k<<<4096, 256, 0, stream>>>(ids, emb, wihf, whhf, wihb, whhb,
                                           bihf, bhhf, bihb, bhhb, xb, wih, whh, bias);
    lstm_rec<<<64, 256, 0, stream>>>(whh, wih, xb, bias, hall, cnt);
    tail_k<<<32, 256, 0, stream>>>(hall, clsw, clsb, label, stp, enp, trp, (float*)d_out);
}